// Round 12
// baseline (195.621 us; speedup 1.0000x reference)
//
#include <hip/hip_runtime.h>
#include <hip/hip_bf16.h>

// B=4, T=1024, E=1024, ATT=64, NH=16, AH=1024. M = B*T = 4096, K = N = 1024.
// Pipeline: cast x->bf16; transpose+cast W{q,k,v,o} -> [N][K] bf16;
//           fused QKV MFMA GEMM (128x128, BK=32 double-buffered pipeline,
//           global_load_lds, K-slab pre-scaled by 0.125*log2e);
//           register-path MFMA flash attention (S^T trick, HW v_exp_f32,
//           key-split 8-wave); O-proj GEMM.

typedef __bf16 bf16_t;
typedef bf16_t bf16x8 __attribute__((ext_vector_type(8)));
typedef bf16_t bf16x4 __attribute__((ext_vector_type(4)));
typedef short  s16x4 __attribute__((ext_vector_type(4)));
typedef float  f32x4 __attribute__((ext_vector_type(4)));

#define SCALE_LOG2E 0.18033688011112042f  /* 0.125 * log2(e) */

__device__ __forceinline__ void async16(const bf16_t* g, void* l) {
    __builtin_amdgcn_global_load_lds(
        (const __attribute__((address_space(1))) unsigned int*)g,
        (__attribute__((address_space(3))) unsigned int*)l,
        16, 0, 0);
}

// ---------- cast fp32 -> bf16, 8 elems/thread ----------
__global__ __launch_bounds__(256) void cast_f32_bf16(
    const float* __restrict__ in, bf16_t* __restrict__ out, int n8)
{
    int i = blockIdx.x * 256 + threadIdx.x;
    if (i >= n8) return;
    const float4* p = (const float4*)in + (size_t)i * 2;
    float4 a = p[0], b = p[1];
    bf16x8 o;
    o[0] = (bf16_t)a.x; o[1] = (bf16_t)a.y; o[2] = (bf16_t)a.z; o[3] = (bf16_t)a.w;
    o[4] = (bf16_t)b.x; o[5] = (bf16_t)b.y; o[6] = (bf16_t)b.z; o[7] = (bf16_t)b.w;
    *((bf16x8*)out + i) = o;
}

// ---------- transpose + cast: W [1024][1024] fp32 [K][N] -> [N][K] bf16 ----------
__global__ __launch_bounds__(256) void transpose_cast(
    const float* __restrict__ W0, const float* __restrict__ W1,
    const float* __restrict__ W2, const float* __restrict__ W3,
    bf16_t* __restrict__ out)
{
    __shared__ float st[32][33];
    const float* W = (blockIdx.z == 0) ? W0 : (blockIdx.z == 1) ? W1
                   : (blockIdx.z == 2) ? W2 : W3;
    bf16_t* o = out + (size_t)blockIdx.z * 1024 * 1024;
    const int n0 = blockIdx.x * 32, k0 = blockIdx.y * 32;
    const int t = threadIdx.x;
    const int r = t >> 3, c4 = (t & 7) * 4;
    float4 v = *(const float4*)(W + (size_t)(k0 + r) * 1024 + n0 + c4);
    st[r][c4 + 0] = v.x; st[r][c4 + 1] = v.y; st[r][c4 + 2] = v.z; st[r][c4 + 3] = v.w;
    __syncthreads();
    bf16_t tmp[4] __attribute__((aligned(8)));
    #pragma unroll
    for (int i = 0; i < 4; ++i) tmp[i] = (bf16_t)st[c4 + i][r];
    *(uint2*)(o + (size_t)(n0 + r) * 1024 + k0 + c4) = *(const uint2*)tmp;
}

// ---------- MFMA GEMM: C = A[M,1024] @ Bt[N,1024]^T + bias ----------
// ROUND 12: software-pipelined LDS double-buffer (T3 "minimum 2-phase"):
// stage K-step t+1 into buf^1 BEFORE computing step t from buf. Previous
// structure issued global_load_lds then IMMEDIATELY barriered, exposing
// full L2/HBM load latency (~200-900 cyc) at every step (m233: that
// stage+drain is ~72% of a 2-phase loop's cost). Now the barrier's vmcnt
// drain lands ~620 cyc after issue -> nearly free. BK=32 x 2 buffers:
// same 32 KB LDS and 32 barriers/block as r9's BK=64 slab-pair (3
// blocks/CU preserved; m132: 64KB dbuf costs occupancy). Staging algebra
// byte-identical to r9 (s-slab index -> buffer index).
template<bool FUSED, int MT>
__global__ __launch_bounds__(256, 3) void gemm_glds(
    const bf16_t* __restrict__ A, const bf16_t* __restrict__ Bt,
    const float* __restrict__ b0, const float* __restrict__ b1,
    const float* __restrict__ b2,
    bf16_t* __restrict__ Qo, bf16_t* __restrict__ Ko, bf16_t* __restrict__ Vo,
    float* __restrict__ Fo)
{
    const int K = 1024;
    __shared__ __align__(16) bf16_t As[2 * MT * 32];
    __shared__ __align__(16) bf16_t Bs[2 * 128 * 32];

    constexpr int NTPW = (MT == 128) ? 4 : 2;
    constexpr int JA   = MT / 64;

    const int tid  = threadIdx.x;
    const int wave = tid >> 6;
    const int lane = tid & 63;
    const int quad = lane >> 4;
    const int l16  = lane & 15;
    const int m0 = blockIdx.y * MT;
    const int n0 = blockIdx.x * 128;
    const int wm = (MT == 128) ? (wave >> 1) * 64 : 0;
    const int wn = (MT == 128) ? (wave & 1) * 64 : wave * 32;

    int goffA[JA], goffB[2];
    #pragma unroll
    for (int j = 0; j < JA; ++j) {
        const int row = j * 64 + (tid >> 2);
        const int cl  = (tid & 3) ^ ((row >> 1) & 3);
        goffA[j] = (m0 + row) * K + cl * 8;
    }
    #pragma unroll
    for (int j = 0; j < 2; ++j) {
        const int row = j * 64 + (tid >> 2);
        const int cl  = (tid & 3) ^ ((row >> 1) & 3);
        goffB[j] = (n0 + row) * K + cl * 8;
    }
    const int ldsoff = wave * 1024;

    f32x4 acc[4][NTPW] = {};
    const int sw = (l16 >> 1) & 3;

    // prologue: stage K-step 0 into buffer 0
    #pragma unroll
    for (int j = 0; j < JA; ++j)
        async16(A + goffA[j], (char*)As + j * 4096 + ldsoff);
    #pragma unroll
    for (int j = 0; j < 2; ++j)
        async16(Bt + goffB[j], (char*)Bs + j * 4096 + ldsoff);
    __syncthreads();   // drains vmcnt: buffer 0 resident

    #pragma unroll 2   // buf parity static per unrolled copy
    for (int k0 = 0; k0 < K; k0 += 32) {
        const int buf = (k0 >> 5) & 1;
        const int nxt = buf ^ 1;

        // issue next K-step's staging into the other buffer BEFORE compute
        if (k0 + 32 < K) {
            #pragma unroll
            for (int j = 0; j < JA; ++j)
                async16(A + goffA[j] + k0 + 32,
                        (char*)As + nxt * (MT * 64) + j * 4096 + ldsoff);
            #pragma unroll
            for (int j = 0; j < 2; ++j)
                async16(Bt + goffB[j] + k0 + 32,
                        (char*)Bs + nxt * 8192 + j * 4096 + ldsoff);
        }

        // compute current buffer
        bf16x8 af[4], bfr[NTPW];
        #pragma unroll
        for (int mt = 0; mt < 4; ++mt)
            af[mt] = *(const bf16x8*)(&As[buf * (MT * 32) +
                (wm + mt * 16 + l16) * 32 + (quad ^ sw) * 8]);
        #pragma unroll
        for (int nt = 0; nt < NTPW; ++nt)
            bfr[nt] = *(const bf16x8*)(&Bs[buf * (128 * 32) +
                (wn + nt * 16 + l16) * 32 + (quad ^ sw) * 8]);
        #pragma unroll
        for (int mt = 0; mt < 4; ++mt)
            #pragma unroll
            for (int nt = 0; nt < NTPW; ++nt)
                acc[mt][nt] = __builtin_amdgcn_mfma_f32_16x16x32_bf16(
                    af[mt], bfr[nt], acc[mt][nt], 0, 0, 0);

        // one barrier per step: drains the (long-since-issued) stage loads
        // and closes the WAR window on buf before it becomes the stage dest.
        __syncthreads();
    }

    if (FUSED) {
        const int sel = n0 >> 10;
        const float* bias = (sel == 0) ? b0 : (sel == 1) ? b1 : b2;
        bf16_t* Cout      = (sel == 0) ? Qo : (sel == 1) ? Ko : Vo;
        const float scl   = (sel == 1) ? SCALE_LOG2E : 1.0f;
        const int nb = n0 & 1023;
        #pragma unroll
        for (int nt = 0; nt < NTPW; ++nt) {
            const int n = nb + wn + nt * 16 + l16;
            const float bb = bias[n];
            #pragma unroll
            for (int mt = 0; mt < 4; ++mt)
                #pragma unroll
                for (int i = 0; i < 4; ++i) {
                    const int m = m0 + wm + mt * 16 + quad * 4 + i;
                    Cout[(size_t)m * 1024 + n] = (bf16_t)((acc[mt][nt][i] + bb) * scl);
                }
        }
    } else {
        #pragma unroll
        for (int nt = 0; nt < NTPW; ++nt) {
            const int n = n0 + wn + nt * 16 + l16;
            const float bb = b0[n];
            #pragma unroll
            for (int mt = 0; mt < 4; ++mt)
                #pragma unroll
                for (int i = 0; i < 4; ++i) {
                    const int m = m0 + wm + mt * 16 + quad * 4 + i;
                    Fo[(size_t)m * 1024 + n] = acc[mt][nt][i] + bb;
                }
        }
    }
}

// ---------- MFMA flash attention, key-split 8-wave (UNCHANGED from r11) ----------
// PARKED at ~54us. r7 barrier-free -2us, r8 key-split -1.5us, r9/r11 pack
// variants +-0.4us. r11's null on a +-14-instr pack swing proves attn is
// latency-bound with large issue slack, not issue-bound. Counters: Mfma 37,
// VALU 58, HBM 10%.
// LEDGER CLOSED r10: inline-asm v_cvt_pk_bf16_f32 after v_exp_f32 => NaN
// (TRANS->asm consumer gets no hazard wait-states). NEVER hand-write it.
__global__ __launch_bounds__(512, 4) void attn_kernel(
    const bf16_t* __restrict__ Q, const bf16_t* __restrict__ K,
    const bf16_t* __restrict__ V, bf16_t* __restrict__ Z)
{
    __shared__ __align__(16) char smem[16 * 1032 * 2];
    bf16_t (*Vt)[1032] = (bf16_t (*)[1032])smem;
    float* cmb = (float*)smem;     // [4 waves][64 lanes][21]

    const int tid  = threadIdx.x;
    const int wave = tid >> 6;        // 0..7
    const int lane = tid & 63;
    const int quad = lane >> 4;
    const int l16  = lane & 15;
    const int hd = blockIdx.x >> 2;
    const int qc = blockIdx.x & 3;
    const int a = hd >> 2, b = hd & 3;
    const int col0 = a * 16;
    const int qw   = wave & 3;
    const int kvh  = wave >> 2;
    const int qbase = qc * 256 + qw * 64;
    const int kb512 = kvh * 512;

    const int r  = tid >> 2;
    const int dq = (tid & 3) * 4;
    const bf16_t* Vp = V + (size_t)(b * 1024 + r) * 1024 + col0 + dq;
    #pragma unroll 2
    for (int t = 0; t < 8; ++t) {
        uint2 vv = *(const uint2*)(Vp + (size_t)(t * 128) * 1024);
        bf16_t t4[4] __attribute__((aligned(8)));
        *(uint2*)t4 = vv;
        #pragma unroll
        for (int ii = 0; ii < 4; ++ii)
            Vt[dq + ii][t * 128 + r] = t4[ii];
    }

    bf16x8 qf[4] = {};
    if (quad < 2) {
        #pragma unroll
        for (int qs = 0; qs < 4; ++qs)
            qf[qs] = *(const bf16x8*)(Q +
                (size_t)(b * 1024 + qbase + qs * 16 + l16) * 1024 + col0 + quad * 8);
    }

    const bf16_t* Kp = K + (size_t)(b * 1024 + kb512 + l16) * 1024 + col0 + quad * 8;
    bf16x8 kfA[4] = {}, kfB[4] = {};
    if (quad < 2) {
        #pragma unroll
        for (int kt = 0; kt < 4; ++kt)
            kfA[kt] = *(const bf16x8*)(Kp + (size_t)(kt * 16) * 1024);
    }

    __syncthreads();   // Vt ready

    const s16x4 ones = { 0x3F80, 0x3F80, 0x3F80, 0x3F80 };  // bf16 1.0 x4

    f32x4 zacc[4] = {};
    f32x4 lacc[4] = {};

#define ATTN_TILE(JIDX, KFCUR, KFNXT, DO_PREFETCH)                            \
    {                                                                         \
        const int j_ = (JIDX);                                                \
        if (DO_PREFETCH && quad < 2) {                                        \
            _Pragma("unroll")                                                 \
            for (int kt = 0; kt < 4; ++kt)                                    \
                KFNXT[kt] = *(const bf16x8*)(                                 \
                    Kp + (size_t)((j_ + 1) * 64 + kt * 16) * 1024);           \
        }                                                                     \
        _Pragma("unroll")                                                     \
        for (int kt = 0; kt < 4; ++kt) {                                      \
            const s16x4 vfrag = __builtin_bit_cast(s16x4,                     \
                *(const uint2*)(&Vt[l16][kb512 + j_ * 64 + kt * 16 + quad * 4])); \
            _Pragma("unroll")                                                 \
            for (int qs = 0; qs < 4; ++qs) {                                  \
                f32x4 zc = {0.f, 0.f, 0.f, 0.f};                              \
                f32x4 s = __builtin_amdgcn_mfma_f32_16x16x32_bf16(            \
                    KFCUR[kt], qf[qs], zc, 0, 0, 0);                          \
                const float e0 = __builtin_amdgcn_exp2f(s[0]);                \
                const float e1 = __builtin_amdgcn_exp2f(s[1]);                \
                const float e2 = __builtin_amdgcn_exp2f(s[2]);                \
                const float e3 = __builtin_amdgcn_exp2f(s[3]);                \
                bf16x4 pv;                                                    \
                pv[0] = (bf16_t)e0; pv[1] = (bf16_t)e1;                       \
                pv[2] = (bf16_t)e2; pv[3] = (bf16_t)e3;                       \
                const s16x4 pfrag = __builtin_bit_cast(s16x4, pv);            \
                zacc[qs] = __builtin_amdgcn_mfma_f32_16x16x16bf16_1k(         \
                    vfrag, pfrag, zacc[qs], 0, 0, 0);                         \
                lacc[qs] = __builtin_amdgcn_mfma_f32_16x16x16bf16_1k(         \
                    ones, pfrag, lacc[qs], 0, 0, 0);                          \
            }                                                                 \
        }                                                                     \
    }

    #pragma unroll 1
    for (int j2 = 0; j2 < 4; ++j2) {
        ATTN_TILE(2 * j2,     kfA, kfB, true)
        ATTN_TILE(2 * j2 + 1, kfB, kfA, (j2 < 3))
    }
#undef ATTN_TILE

    __syncthreads();
    if (wave >= 4) {
        float* p = cmb + ((size_t)((wave - 4) * 64 + lane)) * 21;
        #pragma unroll
        for (int qs = 0; qs < 4; ++qs) {
            #pragma unroll
            for (int i = 0; i < 4; ++i) p[qs * 4 + i] = zacc[qs][i];
            p[16 + qs] = lacc[qs][0];
        }
    }
    __syncthreads();
    if (wave < 4) {
        const float* p = cmb + ((size_t)(wave * 64 + lane)) * 21;
        #pragma unroll
        for (int qs = 0; qs < 4; ++qs) {
            const float inv = 1.0f / (lacc[qs][0] + p[16 + qs]);
            const int q = qbase + qs * 16 + l16;
            bf16_t o4[4] __attribute__((aligned(8)));
            #pragma unroll
            for (int i = 0; i < 4; ++i)
                o4[i] = (bf16_t)((zacc[qs][i] + p[qs * 4 + i]) * inv);
            *(uint2*)(Z + ((size_t)hd * 1024 + q) * 16 + quad * 4) = *(const uint2*)o4;
        }
    }
}

extern "C" void kernel_launch(void* const* d_in, const int* in_sizes, int n_in,
                              void* d_out, int out_size, void* d_ws, size_t ws_size,
                              hipStream_t stream) {
    const float* x  = (const float*)d_in[0];
    const float* Wq = (const float*)d_in[1];
    const float* bq = (const float*)d_in[2];
    const float* Wk = (const float*)d_in[3];
    const float* bk = (const float*)d_in[4];
    const float* Wv = (const float*)d_in[5];
    const float* bv = (const float*)d_in[6];
    const float* Wo = (const float*)d_in[7];
    const float* bo = (const float*)d_in[8];
    float* out = (float*)d_out;

    char* ws = (char*)d_ws;
    bf16_t* x_bf = (bf16_t*)(ws);
    bf16_t* Wt   = (bf16_t*)(ws + (8u << 20));   // q|k|v|o slabs, contiguous
    bf16_t* Qb   = (bf16_t*)(ws + (16u << 20));
    bf16_t* Kb   = (bf16_t*)(ws + (24u << 20));
    bf16_t* Vb   = (bf16_t*)(ws + (32u << 20));
    bf16_t* Zb   = (bf16_t*)(ws + (40u << 20));
    bf16_t* WtO  = Wt + (size_t)3 * 1024 * 1024;

    cast_f32_bf16<<<dim3(2048), dim3(256), 0, stream>>>(x, x_bf, 524288);
    transpose_cast<<<dim3(32, 32, 4), dim3(256), 0, stream>>>(Wq, Wk, Wv, Wo, Wt);

    // fused QKV: Bt = [3072][1024] (Wq|Wk|Wv)
    gemm_glds<true, 128><<<dim3(24, 32), dim3(256), 0, stream>>>(
        x_bf, Wt, bq, bk, bv, Qb, Kb, Vb, nullptr);

    attn_kernel<<<dim3(1024), dim3(512), 0, stream>>>(Qb, Kb, Vb, Zb);

    // O-projection: 64x128 tiles -> 512 blocks (2/CU)
    gemm_glds<false, 64><<<dim3(8, 64), dim3(256), 0, stream>>>(
        Zb, WtO, bo, nullptr, nullptr, nullptr, nullptr, nullptr, out);
}

// Round 13
// 187.085 us; speedup vs baseline: 1.0456x; 1.0456x over previous
//
#include <hip/hip_runtime.h>
#include <hip/hip_bf16.h>

// B=4, T=1024, E=1024, ATT=64, NH=16, AH=1024. M = B*T = 4096, K = N = 1024.
// Pipeline: cast x->bf16; transpose+cast W{q,k,v,o} -> [N][K] bf16;
//           fused QKV MFMA GEMM (128x128, BK=64 slab-pair, global_load_lds,
//           XCD-chunked block swizzle, K-slab pre-scaled by 0.125*log2e);
//           register-path MFMA flash attention (S^T trick, HW v_exp_f32,
//           key-split 8-wave); O-proj GEMM.

typedef __bf16 bf16_t;
typedef bf16_t bf16x8 __attribute__((ext_vector_type(8)));
typedef bf16_t bf16x4 __attribute__((ext_vector_type(4)));
typedef short  s16x4 __attribute__((ext_vector_type(4)));
typedef float  f32x4 __attribute__((ext_vector_type(4)));

#define SCALE_LOG2E 0.18033688011112042f  /* 0.125 * log2(e) */

__device__ __forceinline__ void async16(const bf16_t* g, void* l) {
    __builtin_amdgcn_global_load_lds(
        (const __attribute__((address_space(1))) unsigned int*)g,
        (__attribute__((address_space(3))) unsigned int*)l,
        16, 0, 0);
}

// ---------- cast fp32 -> bf16, 8 elems/thread ----------
__global__ __launch_bounds__(256) void cast_f32_bf16(
    const float* __restrict__ in, bf16_t* __restrict__ out, int n8)
{
    int i = blockIdx.x * 256 + threadIdx.x;
    if (i >= n8) return;
    const float4* p = (const float4*)in + (size_t)i * 2;
    float4 a = p[0], b = p[1];
    bf16x8 o;
    o[0] = (bf16_t)a.x; o[1] = (bf16_t)a.y; o[2] = (bf16_t)a.z; o[3] = (bf16_t)a.w;
    o[4] = (bf16_t)b.x; o[5] = (bf16_t)b.y; o[6] = (bf16_t)b.z; o[7] = (bf16_t)b.w;
    *((bf16x8*)out + i) = o;
}

// ---------- transpose + cast: W [1024][1024] fp32 [K][N] -> [N][K] bf16 ----------
__global__ __launch_bounds__(256) void transpose_cast(
    const float* __restrict__ W0, const float* __restrict__ W1,
    const float* __restrict__ W2, const float* __restrict__ W3,
    bf16_t* __restrict__ out)
{
    __shared__ float st[32][33];
    const float* W = (blockIdx.z == 0) ? W0 : (blockIdx.z == 1) ? W1
                   : (blockIdx.z == 2) ? W2 : W3;
    bf16_t* o = out + (size_t)blockIdx.z * 1024 * 1024;
    const int n0 = blockIdx.x * 32, k0 = blockIdx.y * 32;
    const int t = threadIdx.x;
    const int r = t >> 3, c4 = (t & 7) * 4;
    float4 v = *(const float4*)(W + (size_t)(k0 + r) * 1024 + n0 + c4);
    st[r][c4 + 0] = v.x; st[r][c4 + 1] = v.y; st[r][c4 + 2] = v.z; st[r][c4 + 3] = v.w;
    __syncthreads();
    bf16_t tmp[4] __attribute__((aligned(8)));
    #pragma unroll
    for (int i = 0; i < 4; ++i) tmp[i] = (bf16_t)st[c4 + i][r];
    *(uint2*)(o + (size_t)(n0 + r) * 1024 + k0 + c4) = *(const uint2*)tmp;
}

// ---------- MFMA GEMM: C = A[M,1024] @ Bt[N,1024]^T + bias ----------
// r9 BK=64 slab-pair structure RESTORED (r12's explicit dbuf pipeline
// regressed +9us — m99/m100 confirmed: TLP already covers the drain, and
// 16 MFMAs per barrier amortize worse than 32).
// ROUND 13 ONE CHANGE: XCD-chunked block swizzle (T1). Dispatch is
// x-fastest round-robin across 8 XCDs, so consecutive blocks sharing a
// 256KB A-panel land on different L2s -> A fetched ~8x. Chunked remap
// (flat%8)*(nwg/8) + flat/8 gives each XCD a contiguous run (4 full
// A-panel rows for QKV) -> A fetched once per XCD. nwg = 768 / 512, both
// % 8 == 0 -> simple bijective form valid (ERRATA #11 checked).
template<bool FUSED, int MT>
__global__ __launch_bounds__(256, 3) void gemm_glds(
    const bf16_t* __restrict__ A, const bf16_t* __restrict__ Bt,
    const float* __restrict__ b0, const float* __restrict__ b1,
    const float* __restrict__ b2,
    bf16_t* __restrict__ Qo, bf16_t* __restrict__ Ko, bf16_t* __restrict__ Vo,
    float* __restrict__ Fo)
{
    const int K = 1024;
    __shared__ __align__(16) bf16_t As[2 * MT * 32];
    __shared__ __align__(16) bf16_t Bs[2 * 128 * 32];

    constexpr int NTPW = (MT == 128) ? 4 : 2;
    constexpr int JA   = MT / 64;
    constexpr int NX   = FUSED ? 24 : 8;            // grid.x
    constexpr int NWG  = NX * ((MT == 128) ? 32 : 64);

    const int tid  = threadIdx.x;
    const int wave = tid >> 6;
    const int lane = tid & 63;
    const int quad = lane >> 4;
    const int l16  = lane & 15;

    // XCD-chunked bijective swizzle (work-id from hardware block-id)
    int flat = blockIdx.y * NX + blockIdx.x;
    flat = (flat & 7) * (NWG >> 3) + (flat >> 3);
    const int m0 = (flat / NX) * MT;
    const int n0 = (flat % NX) * 128;

    const int wm = (MT == 128) ? (wave >> 1) * 64 : 0;
    const int wn = (MT == 128) ? (wave & 1) * 64 : wave * 32;

    int goffA[JA], goffB[2];
    #pragma unroll
    for (int j = 0; j < JA; ++j) {
        const int row = j * 64 + (tid >> 2);
        const int cl  = (tid & 3) ^ ((row >> 1) & 3);
        goffA[j] = (m0 + row) * K + cl * 8;
    }
    #pragma unroll
    for (int j = 0; j < 2; ++j) {
        const int row = j * 64 + (tid >> 2);
        const int cl  = (tid & 3) ^ ((row >> 1) & 3);
        goffB[j] = (n0 + row) * K + cl * 8;
    }
    const int ldsoff = wave * 1024;

    f32x4 acc[4][NTPW] = {};
    const int sw = (l16 >> 1) & 3;

    for (int k0 = 0; k0 < K; k0 += 64) {
        #pragma unroll
        for (int s = 0; s < 2; ++s) {
            #pragma unroll
            for (int j = 0; j < JA; ++j)
                async16(A + goffA[j] + k0 + s * 32,
                        (char*)As + s * (MT * 64) + j * 4096 + ldsoff);
            #pragma unroll
            for (int j = 0; j < 2; ++j)
                async16(Bt + goffB[j] + k0 + s * 32,
                        (char*)Bs + s * 8192 + j * 4096 + ldsoff);
        }
        __syncthreads();

        #pragma unroll
        for (int s = 0; s < 2; ++s) {
            bf16x8 af[4], bfr[NTPW];
            #pragma unroll
            for (int mt = 0; mt < 4; ++mt)
                af[mt] = *(const bf16x8*)(&As[s * (MT * 32) +
                    (wm + mt * 16 + l16) * 32 + (quad ^ sw) * 8]);
            #pragma unroll
            for (int nt = 0; nt < NTPW; ++nt)
                bfr[nt] = *(const bf16x8*)(&Bs[s * (128 * 32) +
                    (wn + nt * 16 + l16) * 32 + (quad ^ sw) * 8]);
            #pragma unroll
            for (int mt = 0; mt < 4; ++mt)
                #pragma unroll
                for (int nt = 0; nt < NTPW; ++nt)
                    acc[mt][nt] = __builtin_amdgcn_mfma_f32_16x16x32_bf16(
                        af[mt], bfr[nt], acc[mt][nt], 0, 0, 0);
        }
        __syncthreads();
    }

    if (FUSED) {
        const int sel = n0 >> 10;
        const float* bias = (sel == 0) ? b0 : (sel == 1) ? b1 : b2;
        bf16_t* Cout      = (sel == 0) ? Qo : (sel == 1) ? Ko : Vo;
        const float scl   = (sel == 1) ? SCALE_LOG2E : 1.0f;
        const int nb = n0 & 1023;
        #pragma unroll
        for (int nt = 0; nt < NTPW; ++nt) {
            const int n = nb + wn + nt * 16 + l16;
            const float bb = bias[n];
            #pragma unroll
            for (int mt = 0; mt < 4; ++mt)
                #pragma unroll
                for (int i = 0; i < 4; ++i) {
                    const int m = m0 + wm + mt * 16 + quad * 4 + i;
                    Cout[(size_t)m * 1024 + n] = (bf16_t)((acc[mt][nt][i] + bb) * scl);
                }
        }
    } else {
        #pragma unroll
        for (int nt = 0; nt < NTPW; ++nt) {
            const int n = n0 + wn + nt * 16 + l16;
            const float bb = b0[n];
            #pragma unroll
            for (int mt = 0; mt < 4; ++mt)
                #pragma unroll
                for (int i = 0; i < 4; ++i) {
                    const int m = m0 + wm + mt * 16 + quad * 4 + i;
                    Fo[(size_t)m * 1024 + n] = acc[mt][nt][i] + bb;
                }
        }
    }
}

// ---------- MFMA flash attention, key-split 8-wave (UNCHANGED from r11) ----------
// PARKED at ~54us. r7 barrier-free -2us, r8 key-split -1.5us, r9/r11 pack
// variants +-0.4us. r11's null on a +-14-instr pack swing proves attn is
// latency-bound with large issue slack, not issue-bound. Counters: Mfma 37,
// VALU 58, HBM 10%.
// LEDGER CLOSED r10: inline-asm v_cvt_pk_bf16_f32 after v_exp_f32 => NaN
// (TRANS->asm consumer gets no hazard wait-states). NEVER hand-write it.
__global__ __launch_bounds__(512, 4) void attn_kernel(
    const bf16_t* __restrict__ Q, const bf16_t* __restrict__ K,
    const bf16_t* __restrict__ V, bf16_t* __restrict__ Z)
{
    __shared__ __align__(16) char smem[16 * 1032 * 2];
    bf16_t (*Vt)[1032] = (bf16_t (*)[1032])smem;
    float* cmb = (float*)smem;     // [4 waves][64 lanes][21]

    const int tid  = threadIdx.x;
    const int wave = tid >> 6;        // 0..7
    const int lane = tid & 63;
    const int quad = lane >> 4;
    const int l16  = lane & 15;
    const int hd = blockIdx.x >> 2;
    const int qc = blockIdx.x & 3;
    const int a = hd >> 2, b = hd & 3;
    const int col0 = a * 16;
    const int qw   = wave & 3;
    const int kvh  = wave >> 2;
    const int qbase = qc * 256 + qw * 64;
    const int kb512 = kvh * 512;

    const int r  = tid >> 2;
    const int dq = (tid & 3) * 4;
    const bf16_t* Vp = V + (size_t)(b * 1024 + r) * 1024 + col0 + dq;
    #pragma unroll 2
    for (int t = 0; t < 8; ++t) {
        uint2 vv = *(const uint2*)(Vp + (size_t)(t * 128) * 1024);
        bf16_t t4[4] __attribute__((aligned(8)));
        *(uint2*)t4 = vv;
        #pragma unroll
        for (int ii = 0; ii < 4; ++ii)
            Vt[dq + ii][t * 128 + r] = t4[ii];
    }

    bf16x8 qf[4] = {};
    if (quad < 2) {
        #pragma unroll
        for (int qs = 0; qs < 4; ++qs)
            qf[qs] = *(const bf16x8*)(Q +
                (size_t)(b * 1024 + qbase + qs * 16 + l16) * 1024 + col0 + quad * 8);
    }

    const bf16_t* Kp = K + (size_t)(b * 1024 + kb512 + l16) * 1024 + col0 + quad * 8;
    bf16x8 kfA[4] = {}, kfB[4] = {};
    if (quad < 2) {
        #pragma unroll
        for (int kt = 0; kt < 4; ++kt)
            kfA[kt] = *(const bf16x8*)(Kp + (size_t)(kt * 16) * 1024);
    }

    __syncthreads();   // Vt ready

    const s16x4 ones = { 0x3F80, 0x3F80, 0x3F80, 0x3F80 };  // bf16 1.0 x4

    f32x4 zacc[4] = {};
    f32x4 lacc[4] = {};

#define ATTN_TILE(JIDX, KFCUR, KFNXT, DO_PREFETCH)                            \
    {                                                                         \
        const int j_ = (JIDX);                                                \
        if (DO_PREFETCH && quad < 2) {                                        \
            _Pragma("unroll")                                                 \
            for (int kt = 0; kt < 4; ++kt)                                    \
                KFNXT[kt] = *(const bf16x8*)(                                 \
                    Kp + (size_t)((j_ + 1) * 64 + kt * 16) * 1024);           \
        }                                                                     \
        _Pragma("unroll")                                                     \
        for (int kt = 0; kt < 4; ++kt) {                                      \
            const s16x4 vfrag = __builtin_bit_cast(s16x4,                     \
                *(const uint2*)(&Vt[l16][kb512 + j_ * 64 + kt * 16 + quad * 4])); \
            _Pragma("unroll")                                                 \
            for (int qs = 0; qs < 4; ++qs) {                                  \
                f32x4 zc = {0.f, 0.f, 0.f, 0.f};                              \
                f32x4 s = __builtin_amdgcn_mfma_f32_16x16x32_bf16(            \
                    KFCUR[kt], qf[qs], zc, 0, 0, 0);                          \
                const float e0 = __builtin_amdgcn_exp2f(s[0]);                \
                const float e1 = __builtin_amdgcn_exp2f(s[1]);                \
                const float e2 = __builtin_amdgcn_exp2f(s[2]);                \
                const float e3 = __builtin_amdgcn_exp2f(s[3]);                \
                bf16x4 pv;                                                    \
                pv[0] = (bf16_t)e0; pv[1] = (bf16_t)e1;                       \
                pv[2] = (bf16_t)e2; pv[3] = (bf16_t)e3;                       \
                const s16x4 pfrag = __builtin_bit_cast(s16x4, pv);            \
                zacc[qs] = __builtin_amdgcn_mfma_f32_16x16x16bf16_1k(         \
                    vfrag, pfrag, zacc[qs], 0, 0, 0);                         \
                lacc[qs] = __builtin_amdgcn_mfma_f32_16x16x16bf16_1k(         \
                    ones, pfrag, lacc[qs], 0, 0, 0);                          \
            }                                                                 \
        }                                                                     \
    }

    #pragma unroll 1
    for (int j2 = 0; j2 < 4; ++j2) {
        ATTN_TILE(2 * j2,     kfA, kfB, true)
        ATTN_TILE(2 * j2 + 1, kfB, kfA, (j2 < 3))
    }
#undef ATTN_TILE

    __syncthreads();
    if (wave >= 4) {
        float* p = cmb + ((size_t)((wave - 4) * 64 + lane)) * 21;
        #pragma unroll
        for (int qs = 0; qs < 4; ++qs) {
            #pragma unroll
            for (int i = 0; i < 4; ++i) p[qs * 4 + i] = zacc[qs][i];
            p[16 + qs] = lacc[qs][0];
        }
    }
    __syncthreads();
    if (wave < 4) {
        const float* p = cmb + ((size_t)(wave * 64 + lane)) * 21;
        #pragma unroll
        for (int qs = 0; qs < 4; ++qs) {
            const float inv = 1.0f / (lacc[qs][0] + p[16 + qs]);
            const int q = qbase + qs * 16 + l16;
            bf16_t o4[4] __attribute__((aligned(8)));
            #pragma unroll
            for (int i = 0; i < 4; ++i)
                o4[i] = (bf16_t)((zacc[qs][i] + p[qs * 4 + i]) * inv);
            *(uint2*)(Z + ((size_t)hd * 1024 + q) * 16 + quad * 4) = *(const uint2*)o4;
        }
    }
}

extern "C" void kernel_launch(void* const* d_in, const int* in_sizes, int n_in,
                              void* d_out, int out_size, void* d_ws, size_t ws_size,
                              hipStream_t stream) {
    const float* x  = (const float*)d_in[0];
    const float* Wq = (const float*)d_in[1];
    const float* bq = (const float*)d_in[2];
    const float* Wk = (const float*)d_in[3];
    const float* bk = (const float*)d_in[4];
    const float* Wv = (const float*)d_in[5];
    const float* bv = (const float*)d_in[6];
    const float* Wo = (const float*)d_in[7];
    const float* bo = (const float*)d_in[8];
    float* out = (float*)d_out;

    char* ws = (char*)d_ws;
    bf16_t* x_bf = (bf16_t*)(ws);
    bf16_t* Wt   = (bf16_t*)(ws + (8u << 20));   // q|k|v|o slabs, contiguous
    bf16_t* Qb   = (bf16_t*)(ws + (16u << 20));
    bf16_t* Kb   = (bf16_t*)(ws + (24u << 20));
    bf16_t* Vb   = (bf16_t*)(ws + (32u << 20));
    bf16_t* Zb   = (bf16_t*)(ws + (40u << 20));
    bf16_t* WtO  = Wt + (size_t)3 * 1024 * 1024;

    cast_f32_bf16<<<dim3(2048), dim3(256), 0, stream>>>(x, x_bf, 524288);
    transpose_cast<<<dim3(32, 32, 4), dim3(256), 0, stream>>>(Wq, Wk, Wv, Wo, Wt);

    // fused QKV: Bt = [3072][1024] (Wq|Wk|Wv)
    gemm_glds<true, 128><<<dim3(24, 32), dim3(256), 0, stream>>>(
        x_bf, Wt, bq, bk, bv, Qb, Kb, Vb, nullptr);

    attn_kernel<<<dim3(1024), dim3(512), 0, stream>>>(Qb, Kb, Vb, Zb);

    // O-projection: 64x128 tiles -> 512 blocks (2/CU)
    gemm_glds<false, 64><<<dim3(8, 64), dim3(256), 0, stream>>>(
        Zb, WtO, bo, nullptr, nullptr, nullptr, nullptr, nullptr, out);
}

// Round 14
// 180.735 us; speedup vs baseline: 1.0824x; 1.0351x over previous
//
#include <hip/hip_runtime.h>
#include <hip/hip_bf16.h>

// B=4, T=1024, E=1024, ATT=64, NH=16, AH=1024. M = B*T = 4096, K = N = 1024.
// Pipeline: cast x->bf16; transpose+cast W{q,k,v,o} -> [N][K] bf16;
//           fused QKV MFMA GEMM (128x128, BK=64 slab-pair, global_load_lds,
//           XCD-chunked swizzle, HEAD-MAJOR Q/K/V epilogue layout, K-slab
//           pre-scaled by 0.125*log2e); register-path MFMA flash attention
//           (S^T trick, HW v_exp_f32, key-split 8-wave); O-proj GEMM.
//
// ROUND 14: head-major QKV layout. head_dim=16 made every attn access a
// 32B slice of a 2KB-stride row: each kf load = 32 scattered cache lines,
// half of every line wasted (FETCH 36.9MB, latency-bound loads — r11's
// diagnosis). Q/K/V now stored as [a][m][d], addr = a*65536 + m*16 + d
// (a = head, m = b*1024+t, d<16): each head slice is a dense 32KB block,
// every attn load a fully-coalesced 512B/wave burst. Producer-side change
// only (GEMM epilogue index algebra); Z/O-proj untouched.

typedef __bf16 bf16_t;
typedef bf16_t bf16x8 __attribute__((ext_vector_type(8)));
typedef bf16_t bf16x4 __attribute__((ext_vector_type(4)));
typedef short  s16x4 __attribute__((ext_vector_type(4)));
typedef float  f32x4 __attribute__((ext_vector_type(4)));

#define SCALE_LOG2E 0.18033688011112042f  /* 0.125 * log2(e) */

__device__ __forceinline__ void async16(const bf16_t* g, void* l) {
    __builtin_amdgcn_global_load_lds(
        (const __attribute__((address_space(1))) unsigned int*)g,
        (__attribute__((address_space(3))) unsigned int*)l,
        16, 0, 0);
}

// ---------- cast fp32 -> bf16, 8 elems/thread ----------
__global__ __launch_bounds__(256) void cast_f32_bf16(
    const float* __restrict__ in, bf16_t* __restrict__ out, int n8)
{
    int i = blockIdx.x * 256 + threadIdx.x;
    if (i >= n8) return;
    const float4* p = (const float4*)in + (size_t)i * 2;
    float4 a = p[0], b = p[1];
    bf16x8 o;
    o[0] = (bf16_t)a.x; o[1] = (bf16_t)a.y; o[2] = (bf16_t)a.z; o[3] = (bf16_t)a.w;
    o[4] = (bf16_t)b.x; o[5] = (bf16_t)b.y; o[6] = (bf16_t)b.z; o[7] = (bf16_t)b.w;
    *((bf16x8*)out + i) = o;
}

// ---------- transpose + cast: W [1024][1024] fp32 [K][N] -> [N][K] bf16 ----------
__global__ __launch_bounds__(256) void transpose_cast(
    const float* __restrict__ W0, const float* __restrict__ W1,
    const float* __restrict__ W2, const float* __restrict__ W3,
    bf16_t* __restrict__ out)
{
    __shared__ float st[32][33];
    const float* W = (blockIdx.z == 0) ? W0 : (blockIdx.z == 1) ? W1
                   : (blockIdx.z == 2) ? W2 : W3;
    bf16_t* o = out + (size_t)blockIdx.z * 1024 * 1024;
    const int n0 = blockIdx.x * 32, k0 = blockIdx.y * 32;
    const int t = threadIdx.x;
    const int r = t >> 3, c4 = (t & 7) * 4;
    float4 v = *(const float4*)(W + (size_t)(k0 + r) * 1024 + n0 + c4);
    st[r][c4 + 0] = v.x; st[r][c4 + 1] = v.y; st[r][c4 + 2] = v.z; st[r][c4 + 3] = v.w;
    __syncthreads();
    bf16_t tmp[4] __attribute__((aligned(8)));
    #pragma unroll
    for (int i = 0; i < 4; ++i) tmp[i] = (bf16_t)st[c4 + i][r];
    *(uint2*)(o + (size_t)(n0 + r) * 1024 + k0 + c4) = *(const uint2*)tmp;
}

// ---------- MFMA GEMM: C = A[M,1024] @ Bt[N,1024]^T + bias ----------
// r9 BK=64 slab-pair (best GEMM structure: r12 explicit dbuf regressed).
// XCD-chunked swizzle kept from r13 (neutral, harmless — L3 absorbs).
// FUSED epilogue writes HEAD-MAJOR: addr = (n>>4)*65536 + m*16 + (n&15).
template<bool FUSED, int MT>
__global__ __launch_bounds__(256, 3) void gemm_glds(
    const bf16_t* __restrict__ A, const bf16_t* __restrict__ Bt,
    const float* __restrict__ b0, const float* __restrict__ b1,
    const float* __restrict__ b2,
    bf16_t* __restrict__ Qo, bf16_t* __restrict__ Ko, bf16_t* __restrict__ Vo,
    float* __restrict__ Fo)
{
    const int K = 1024;
    __shared__ __align__(16) bf16_t As[2 * MT * 32];
    __shared__ __align__(16) bf16_t Bs[2 * 128 * 32];

    constexpr int NTPW = (MT == 128) ? 4 : 2;
    constexpr int JA   = MT / 64;
    constexpr int NX   = FUSED ? 24 : 8;            // grid.x
    constexpr int NWG  = NX * ((MT == 128) ? 32 : 64);

    const int tid  = threadIdx.x;
    const int wave = tid >> 6;
    const int lane = tid & 63;
    const int quad = lane >> 4;
    const int l16  = lane & 15;

    // XCD-chunked bijective swizzle (NWG % 8 == 0 for both instantiations)
    int flat = blockIdx.y * NX + blockIdx.x;
    flat = (flat & 7) * (NWG >> 3) + (flat >> 3);
    const int m0 = (flat / NX) * MT;
    const int n0 = (flat % NX) * 128;

    const int wm = (MT == 128) ? (wave >> 1) * 64 : 0;
    const int wn = (MT == 128) ? (wave & 1) * 64 : wave * 32;

    int goffA[JA], goffB[2];
    #pragma unroll
    for (int j = 0; j < JA; ++j) {
        const int row = j * 64 + (tid >> 2);
        const int cl  = (tid & 3) ^ ((row >> 1) & 3);
        goffA[j] = (m0 + row) * K + cl * 8;
    }
    #pragma unroll
    for (int j = 0; j < 2; ++j) {
        const int row = j * 64 + (tid >> 2);
        const int cl  = (tid & 3) ^ ((row >> 1) & 3);
        goffB[j] = (n0 + row) * K + cl * 8;
    }
    const int ldsoff = wave * 1024;

    f32x4 acc[4][NTPW] = {};
    const int sw = (l16 >> 1) & 3;

    for (int k0 = 0; k0 < K; k0 += 64) {
        #pragma unroll
        for (int s = 0; s < 2; ++s) {
            #pragma unroll
            for (int j = 0; j < JA; ++j)
                async16(A + goffA[j] + k0 + s * 32,
                        (char*)As + s * (MT * 64) + j * 4096 + ldsoff);
            #pragma unroll
            for (int j = 0; j < 2; ++j)
                async16(Bt + goffB[j] + k0 + s * 32,
                        (char*)Bs + s * 8192 + j * 4096 + ldsoff);
        }
        __syncthreads();

        #pragma unroll
        for (int s = 0; s < 2; ++s) {
            bf16x8 af[4], bfr[NTPW];
            #pragma unroll
            for (int mt = 0; mt < 4; ++mt)
                af[mt] = *(const bf16x8*)(&As[s * (MT * 32) +
                    (wm + mt * 16 + l16) * 32 + (quad ^ sw) * 8]);
            #pragma unroll
            for (int nt = 0; nt < NTPW; ++nt)
                bfr[nt] = *(const bf16x8*)(&Bs[s * (128 * 32) +
                    (wn + nt * 16 + l16) * 32 + (quad ^ sw) * 8]);
            #pragma unroll
            for (int mt = 0; mt < 4; ++mt)
                #pragma unroll
                for (int nt = 0; nt < NTPW; ++nt)
                    acc[mt][nt] = __builtin_amdgcn_mfma_f32_16x16x32_bf16(
                        af[mt], bfr[nt], acc[mt][nt], 0, 0, 0);
        }
        __syncthreads();
    }

    if (FUSED) {
        const int sel = n0 >> 10;
        const float* bias = (sel == 0) ? b0 : (sel == 1) ? b1 : b2;
        bf16_t* Cout      = (sel == 0) ? Qo : (sel == 1) ? Ko : Vo;
        const float scl   = (sel == 1) ? SCALE_LOG2E : 1.0f;
        const int nb = n0 & 1023;
        #pragma unroll
        for (int nt = 0; nt < NTPW; ++nt) {
            const int n = nb + wn + nt * 16 + l16;
            const float bb = bias[n];
            // head-major: addr = (n>>4)*65536 + m*16 + (n&15)
            const size_t hbase = (size_t)(n >> 4) * 65536 + (n & 15);
            #pragma unroll
            for (int mt = 0; mt < 4; ++mt)
                #pragma unroll
                for (int i = 0; i < 4; ++i) {
                    const int m = m0 + wm + mt * 16 + quad * 4 + i;
                    Cout[hbase + (size_t)m * 16] = (bf16_t)((acc[mt][nt][i] + bb) * scl);
                }
        }
    } else {
        #pragma unroll
        for (int nt = 0; nt < NTPW; ++nt) {
            const int n = n0 + wn + nt * 16 + l16;
            const float bb = b0[n];
            #pragma unroll
            for (int mt = 0; mt < 4; ++mt)
                #pragma unroll
                for (int i = 0; i < 4; ++i) {
                    const int m = m0 + wm + mt * 16 + quad * 4 + i;
                    Fo[(size_t)m * 1024 + n] = acc[mt][nt][i] + bb;
                }
        }
    }
}

// ---------- MFMA flash attention, key-split 8-wave, head-major inputs ----------
// Structure = r8/r11 (proven): grid 1024, 512 thr = 8 waves; waves 0-3 key
// tiles 0-7, waves 4-7 key tiles 8-15 (same q rows); additive partial
// combine via LDS; full-head V^T staged once; barrier-free main loop;
// kfA/kfB named K dbuf. ONLY the Q/K/V global addressing changed to the
// head-major layout: every load is now a dense 512B/wave coalesced burst
// (was: 32 scattered lines per instr at 2KB stride).
// LEDGER: r10 inline-asm cvt_pk after v_exp => NaN (no hazard wait) — never
// hand-write. r11: pack-width null => attn latency-bound, issue slack.
__global__ __launch_bounds__(512, 4) void attn_kernel(
    const bf16_t* __restrict__ Q, const bf16_t* __restrict__ K,
    const bf16_t* __restrict__ V, bf16_t* __restrict__ Z)
{
    __shared__ __align__(16) char smem[16 * 1032 * 2];
    bf16_t (*Vt)[1032] = (bf16_t (*)[1032])smem;
    float* cmb = (float*)smem;     // [4 waves][64 lanes][21]

    const int tid  = threadIdx.x;
    const int wave = tid >> 6;        // 0..7
    const int lane = tid & 63;
    const int quad = lane >> 4;
    const int l16  = lane & 15;
    const int hd = blockIdx.x >> 2;
    const int qc = blockIdx.x & 3;
    const int a = hd >> 2, b = hd & 3;
    const int qw   = wave & 3;
    const int kvh  = wave >> 2;
    const int qbase = qc * 256 + qw * 64;
    const int kb512 = kvh * 512;

    // head-major base: head a at a*65536, row m = b*1024 + t, 16 elems/row
    const size_t hb = (size_t)a * 65536 + (size_t)b * 1024 * 16;

    // ---- stage full V^T: thread (r=tid>>2 in 0..127, dq=(tid&3)*4) ----
    const int r  = tid >> 2;
    const int dq = (tid & 3) * 4;
    const bf16_t* Vp = V + hb + (size_t)r * 16 + dq;
    #pragma unroll 2
    for (int t = 0; t < 8; ++t) {
        uint2 vv = *(const uint2*)(Vp + t * 2048);   // +128 rows
        bf16_t t4[4] __attribute__((aligned(8)));
        *(uint2*)t4 = vv;
        #pragma unroll
        for (int ii = 0; ii < 4; ++ii)
            Vt[dq + ii][t * 128 + r] = t4[ii];
    }

    // Q as B-operand of S^T: B[n=q=l16][k=d=quad*8+j], quads 2,3 zero (d<16)
    bf16x8 qf[4] = {};
    if (quad < 2) {
        #pragma unroll
        for (int qs = 0; qs < 4; ++qs)
            qf[qs] = *(const bf16x8*)(Q + hb +
                (size_t)(qbase + qs * 16 + l16) * 16 + quad * 8);
    }

    // K for this wave's key half: A[m=key=l16][k=d=quad*8+j], named dbuf
    const bf16_t* Kp = K + hb + (size_t)(kb512 + l16) * 16 + quad * 8;
    bf16x8 kfA[4] = {}, kfB[4] = {};
    if (quad < 2) {
        #pragma unroll
        for (int kt = 0; kt < 4; ++kt)
            kfA[kt] = *(const bf16x8*)(Kp + kt * 256);   // +16 rows
    }

    __syncthreads();   // Vt ready

    const s16x4 ones = { 0x3F80, 0x3F80, 0x3F80, 0x3F80 };  // bf16 1.0 x4

    f32x4 zacc[4] = {};
    f32x4 lacc[4] = {};

#define ATTN_TILE(JIDX, KFCUR, KFNXT, DO_PREFETCH)                            \
    {                                                                         \
        const int j_ = (JIDX);                                                \
        if (DO_PREFETCH && quad < 2) {                                        \
            _Pragma("unroll")                                                 \
            for (int kt = 0; kt < 4; ++kt)                                    \
                KFNXT[kt] = *(const bf16x8*)(                                 \
                    Kp + (j_ + 1) * 1024 + kt * 256);                         \
        }                                                                     \
        _Pragma("unroll")                                                     \
        for (int kt = 0; kt < 4; ++kt) {                                      \
            const s16x4 vfrag = __builtin_bit_cast(s16x4,                     \
                *(const uint2*)(&Vt[l16][kb512 + j_ * 64 + kt * 16 + quad * 4])); \
            _Pragma("unroll")                                                 \
            for (int qs = 0; qs < 4; ++qs) {                                  \
                f32x4 zc = {0.f, 0.f, 0.f, 0.f};                              \
                f32x4 s = __builtin_amdgcn_mfma_f32_16x16x32_bf16(            \
                    KFCUR[kt], qf[qs], zc, 0, 0, 0);                          \
                const float e0 = __builtin_amdgcn_exp2f(s[0]);                \
                const float e1 = __builtin_amdgcn_exp2f(s[1]);                \
                const float e2 = __builtin_amdgcn_exp2f(s[2]);                \
                const float e3 = __builtin_amdgcn_exp2f(s[3]);                \
                bf16x4 pv;                                                    \
                pv[0] = (bf16_t)e0; pv[1] = (bf16_t)e1;                       \
                pv[2] = (bf16_t)e2; pv[3] = (bf16_t)e3;                       \
                const s16x4 pfrag = __builtin_bit_cast(s16x4, pv);            \
                zacc[qs] = __builtin_amdgcn_mfma_f32_16x16x16bf16_1k(         \
                    vfrag, pfrag, zacc[qs], 0, 0, 0);                         \
                lacc[qs] = __builtin_amdgcn_mfma_f32_16x16x16bf16_1k(         \
                    ones, pfrag, lacc[qs], 0, 0, 0);                          \
            }                                                                 \
        }                                                                     \
    }

    #pragma unroll 1
    for (int j2 = 0; j2 < 4; ++j2) {
        ATTN_TILE(2 * j2,     kfA, kfB, true)
        ATTN_TILE(2 * j2 + 1, kfB, kfA, (j2 < 3))
    }
#undef ATTN_TILE

    __syncthreads();
    if (wave >= 4) {
        float* p = cmb + ((size_t)((wave - 4) * 64 + lane)) * 21;
        #pragma unroll
        for (int qs = 0; qs < 4; ++qs) {
            #pragma unroll
            for (int i = 0; i < 4; ++i) p[qs * 4 + i] = zacc[qs][i];
            p[16 + qs] = lacc[qs][0];
        }
    }
    __syncthreads();
    if (wave < 4) {
        const float* p = cmb + ((size_t)(wave * 64 + lane)) * 21;
        #pragma unroll
        for (int qs = 0; qs < 4; ++qs) {
            const float inv = 1.0f / (lacc[qs][0] + p[16 + qs]);
            const int q = qbase + qs * 16 + l16;
            bf16_t o4[4] __attribute__((aligned(8)));
            #pragma unroll
            for (int i = 0; i < 4; ++i)
                o4[i] = (bf16_t)((zacc[qs][i] + p[qs * 4 + i]) * inv);
            *(uint2*)(Z + ((size_t)hd * 1024 + q) * 16 + quad * 4) = *(const uint2*)o4;
        }
    }
}

extern "C" void kernel_launch(void* const* d_in, const int* in_sizes, int n_in,
                              void* d_out, int out_size, void* d_ws, size_t ws_size,
                              hipStream_t stream) {
    const float* x  = (const float*)d_in[0];
    const float* Wq = (const float*)d_in[1];
    const float* bq = (const float*)d_in[2];
    const float* Wk = (const float*)d_in[3];
    const float* bk = (const float*)d_in[4];
    const float* Wv = (const float*)d_in[5];
    const float* bv = (const float*)d_in[6];
    const float* Wo = (const float*)d_in[7];
    const float* bo = (const float*)d_in[8];
    float* out = (float*)d_out;

    char* ws = (char*)d_ws;
    bf16_t* x_bf = (bf16_t*)(ws);
    bf16_t* Wt   = (bf16_t*)(ws + (8u << 20));   // q|k|v|o slabs, contiguous
    bf16_t* Qb   = (bf16_t*)(ws + (16u << 20));
    bf16_t* Kb   = (bf16_t*)(ws + (24u << 20));
    bf16_t* Vb   = (bf16_t*)(ws + (32u << 20));
    bf16_t* Zb   = (bf16_t*)(ws + (40u << 20));
    bf16_t* WtO  = Wt + (size_t)3 * 1024 * 1024;

    cast_f32_bf16<<<dim3(2048), dim3(256), 0, stream>>>(x, x_bf, 524288);
    transpose_cast<<<dim3(32, 32, 4), dim3(256), 0, stream>>>(Wq, Wk, Wv, Wo, Wt);

    // fused QKV: Bt = [3072][1024] (Wq|Wk|Wv); Q/K/V written head-major
    gemm_glds<true, 128><<<dim3(24, 32), dim3(256), 0, stream>>>(
        x_bf, Wt, bq, bk, bv, Qb, Kb, Vb, nullptr);

    attn_kernel<<<dim3(1024), dim3(512), 0, stream>>>(Qb, Kb, Vb, Zb);

    // O-projection: 64x128 tiles -> 512 blocks (2/CU)
    gemm_glds<false, 64><<<dim3(8, 64), dim3(256), 0, stream>>>(
        Zb, WtO, bo, nullptr, nullptr, nullptr, nullptr, nullptr, out);
}